// Round 3
// baseline (202.178 us; speedup 1.0000x reference)
//
#include <hip/hip_runtime.h>
#include <hip/hip_bf16.h>

// Problem constants (from reference)
#define B_  2
#define F_  2
#define C_  64
#define D_  96
#define HM_ 48
#define WM_ 160
#define HW_ (HM_ * WM_)                 // 7680
#define NTOT ((size_t)B_ * D_ * HW_)    // 1,474,560 per output tensor
#define EPS_ 1e-7f

typedef float f32x2 __attribute__((ext_vector_type(2)));

// ---------------------------------------------------------------------------
// Precompute P = (K @ T)[:3] per (b,f) (12 floats each) and pose validity.
// ---------------------------------------------------------------------------
__global__ void setup_proj(const float* __restrict__ poses,
                           const float* __restrict__ K,
                           float* __restrict__ Pout,      // [B*F][12]
                           float* __restrict__ validOut)  // [B*F]
{
    int t = threadIdx.x;
    if (t < B_ * F_ * 12) {
        int j  = t & 3;
        int i  = (t >> 2) % 3;
        int bf = t / 12;
        int b  = bf / F_;
        const float* Kb = K + (size_t)b * 16;
        const float* T  = poses + (size_t)bf * 16;
        float s = 0.f;
        #pragma unroll
        for (int k = 0; k < 4; ++k) s += Kb[i * 4 + k] * T[k * 4 + j];
        Pout[bf * 12 + i * 4 + j] = s;
    }
    if (t < B_ * F_) {
        const float* T = poses + (size_t)t * 16;
        float s = 0.f;
        #pragma unroll
        for (int k = 0; k < 16; ++k) s += T[k];
        validOut[t] = (s != 0.0f) ? 1.0f : 0.0f;
    }
}

// ---------------------------------------------------------------------------
// Main cost-volume kernel. One thread per output (b,d,hw).
// Key facts used:
//  * edge factor nonzero  =>  gx in [2,158], gy in [2,46]  =>  all 4 bilinear
//    corners strictly in-bounds => no per-corner validity logic needed.
//    Out-of-edge lanes only need fault-safe (clamped) addresses; their
//    contribution is multiplied by factor==0.
//  * corners (x0,y) and (x0+1,y) are adjacent floats => one 8B load per row.
// ---------------------------------------------------------------------------
__global__ __launch_bounds__(256) void cost_volume(
    const float* __restrict__ cur,     // [B][C][HW]
    const float* __restrict__ look,    // [B][F][C][HW]
    const float* __restrict__ invK,    // [B][16]
    const float* __restrict__ P,       // [B*F][12]
    const float* __restrict__ validF,  // [B*F]
    float* __restrict__ cvOut)         // [B][D][HW]
{
    int gid  = blockIdx.x * 256 + threadIdx.x;   // exact: B*D*HW = 5760*256
    int hw   = gid % HW_;
    int rest = gid / HW_;      // uniform within a block
    int d    = rest % D_;
    int b    = rest / D_;

    int x = hw % WM_, y = hw / WM_;
    float fx = (float)x, fy = (float)y;

    const float* ik = invK + (size_t)b * 16;
    float rx = ik[0] * fx + ik[1] * fy + ik[2];
    float ry = ik[4] * fx + ik[5] * fy + ik[6];
    float rz = ik[8] * fx + ik[9] * fy + ik[10];

    float depth = 0.1f + (float)d * (19.9f / 95.0f);
    float qx = depth * rx, qy = depth * ry, qz = depth * rz;

    bool inter = (x >= 2 && x <= WM_ - 3 && y >= 2 && y <= HM_ - 3);

    int   o0[F_], o1[F_];            // row offsets (channel 0, element units)
    float w00[F_], w01[F_], w02[F_], w03[F_];  // premultiplied bilinear weights
    float ff[F_];                    // edge * valid

    #pragma unroll
    for (int f = 0; f < F_; ++f) {
        const float* Pf = P + (size_t)(b * F_ + f) * 12;
        float cp0 = Pf[0] * qx + Pf[1] * qy + Pf[2]  * qz + Pf[3];
        float cp1 = Pf[4] * qx + Pf[5] * qy + Pf[6]  * qz + Pf[7];
        float cp2 = Pf[8] * qx + Pf[9] * qy + Pf[10] * qz + Pf[11];
        float z  = cp2 + EPS_;
        float gx = cp0 / z, gy = cp1 / z;

        float x0f = floorf(gx), y0f = floorf(gy);
        float wx1 = gx - x0f, wy1 = gy - y0f;
        float wx0 = 1.f - wx1, wy0 = 1.f - wy1;

        // fault-safe addresses (no-ops for edge-active lanes)
        int x0 = (int)x0f, y0 = (int)y0f;
        int cx = min(max(x0, 0), WM_ - 2);
        int cy0 = min(max(y0,     0), HM_ - 1);
        int cy1 = min(max(y0 + 1, 0), HM_ - 1);

        int fb = (b * F_ + f) * C_ * HW_;      // frame base (channel 0)
        o0[f] = fb + cy0 * WM_ + cx;
        o1[f] = fb + cy1 * WM_ + cx;

        w00[f] = wx0 * wy0;   // (x0,y0)
        w01[f] = wx1 * wy0;   // (x0+1,y0)
        w02[f] = wx0 * wy1;   // (x0,y1)
        w03[f] = wx1 * wy1;   // (x0+1,y1)

        bool e = (gx >= 2.f) && (gx <= (float)(WM_ - 2)) &&
                 (gy >= 2.f) && (gy <= (float)(HM_ - 2)) && inter;
        ff[f] = (e ? 1.f : 0.f) * validF[b * F_ + f];
    }

    // Wave-uniform early-out
    if (__ballot(ff[0] > 0.f || ff[1] > 0.f) == 0ull) {
        cvOut[(size_t)gid] = 0.f;
        return;
    }

    const float* cp  = cur + (size_t)(b * C_ * HW_ + hw);
    const float* lr00 = look + o0[0];
    const float* lr01 = look + o1[0];
    const float* lr10 = look + o0[1];
    const float* lr11 = look + o1[1];

    float s0 = 0.f, s1 = 0.f;
    #pragma unroll 4
    for (int c = 0; c < C_; ++c) {
        float cvv = cp[(size_t)c * HW_];
        f32x2 r00, r01, r10, r11;
        __builtin_memcpy(&r00, lr00 + (size_t)c * HW_, 8);
        __builtin_memcpy(&r01, lr01 + (size_t)c * HW_, 8);
        __builtin_memcpy(&r10, lr10 + (size_t)c * HW_, 8);
        __builtin_memcpy(&r11, lr11 + (size_t)c * HW_, 8);

        float a0 = fmaf(w00[0], r00.x, fmaf(w01[0], r00.y,
                   fmaf(w02[0], r01.x, w03[0] * r01.y)));
        float a1 = fmaf(w00[1], r10.x, fmaf(w01[1], r10.y,
                   fmaf(w02[1], r11.x, w03[1] * r11.y)));
        s0 += fabsf(a0 - cvv);
        s1 += fabsf(a1 - cvv);
    }

    float m0 = s0 * (1.0f / 64.0f) * ff[0];
    float m1 = s1 * (1.0f / 64.0f) * ff[1];
    float costsum = m0 + m1;
    float counts  = ((m0 > 0.f) ? 1.f : 0.f) + ((m1 > 0.f) ? 1.f : 0.f);
    // counts==0 -> costsum==0 -> result 0 for any finite scale
    float scale = (counts > 1.5f) ? (1.0f / (2.0f + EPS_)) : (1.0f / (1.0f + EPS_));
    cvOut[(size_t)gid] = costsum * scale;
}

// ---------------------------------------------------------------------------
// Finalize: per (b,hw), max over D, then write cost / missing.
// ---------------------------------------------------------------------------
__global__ __launch_bounds__(256) void finalize(
    const float* __restrict__ cv,   // [B][D][HW]
    float* __restrict__ cost,       // [B][D][HW]
    float* __restrict__ missing)    // [B][D][HW]
{
    int t = blockIdx.x * blockDim.x + threadIdx.x;
    if (t >= B_ * HW_) return;
    int b = t / HW_, hw = t % HW_;
    const float* src = cv + (size_t)b * D_ * HW_ + hw;

    float mx = 0.f;   // all values >= 0
    for (int d = 0; d < D_; ++d)
        mx = fmaxf(mx, src[(size_t)d * HW_]);

    for (int d = 0; d < D_; ++d) {
        float v = src[(size_t)d * HW_];
        float m = (v == 0.f) ? 1.f : 0.f;
        size_t o = (size_t)b * D_ * HW_ + (size_t)d * HW_ + hw;
        cost[o]    = (m != 0.f) ? mx : v;
        missing[o] = m;
    }
}

// ---------------------------------------------------------------------------
extern "C" void kernel_launch(void* const* d_in, const int* in_sizes, int n_in,
                              void* d_out, int out_size, void* d_ws, size_t ws_size,
                              hipStream_t stream)
{
    const float* current = (const float*)d_in[0];  // [B,C,H,W]
    const float* lookup  = (const float*)d_in[1];  // [B,F,C,H,W]
    const float* poses   = (const float*)d_in[2];  // [B,F,4,4]
    const float* K       = (const float*)d_in[3];  // [B,4,4]
    const float* invK    = (const float*)d_in[4];  // [B,4,4]

    float* out = (float*)d_out;
    float* costOut    = out;                 // [B,D,H,W]
    float* missingOut = out + NTOT;          // [B,D,H,W]
    float* cvOut      = out + 2 * NTOT;      // [B,D,H,W] (pre-fill cost)

    float* ws     = (float*)d_ws;
    float* Pmat   = ws;                      // B*F*12 = 48
    float* validF = Pmat + B_ * F_ * 12;     // B*F    = 4

    hipLaunchKernelGGL(setup_proj, dim3(1), dim3(64), 0, stream,
                       poses, K, Pmat, validF);

    const int total = B_ * D_ * HW_;            // 1,474,560 = 5760 * 256
    hipLaunchKernelGGL(cost_volume, dim3(total / 256), dim3(256), 0, stream,
                       current, lookup, invK, Pmat, validF, cvOut);

    const int npix = B_ * HW_;                  // 15,360
    hipLaunchKernelGGL(finalize, dim3((npix + 255) / 256), dim3(256), 0, stream,
                       cvOut, costOut, missingOut);
}

// Round 4
// 147.072 us; speedup vs baseline: 1.3747x; 1.3747x over previous
//
#include <hip/hip_runtime.h>
#include <hip/hip_bf16.h>
#include <stdint.h>

// Problem constants (from reference)
#define B_  2
#define F_  2
#define C_  64
#define D_  96
#define HM_ 48
#define WM_ 160
#define HW_ (HM_ * WM_)                 // 7680
#define NTOT ((size_t)B_ * D_ * HW_)    // 1,474,560 per output tensor
#define EPS_ 1e-7f

// bf16 round-to-nearest-even from float bits (finite inputs)
__device__ __forceinline__ uint32_t f2bf(float f) {
    uint32_t u = __float_as_uint(f);
    return (u + 0x7FFFu + ((u >> 16) & 1u)) >> 16;
}

// ---------------------------------------------------------------------------
// Pack, for each (frame,channel,y,x), the 2x2 bilinear corner quad as 4xbf16
// in one aligned uint2:  w0 = bf(v[y][x]) | bf(v[y][x+1])<<16
//                        w1 = bf(v[y+1][x]) | bf(v[y+1][x+1])<<16
// Neighbors clamped at the border (only ff==0 lanes ever read those).
// ---------------------------------------------------------------------------
__global__ __launch_bounds__(256) void pack_quads(
    const float* __restrict__ look,   // [B*F][C][HW]
    uint2* __restrict__ quad)         // [B*F*C*HW]
{
    int t = blockIdx.x * 256 + threadIdx.x;   // exact: B*F*C*HW = 7680*256
    int hw = t % HW_;
    int n  = t / HW_;
    int x = hw % WM_, y = hw / WM_;
    int x1 = min(x + 1, WM_ - 1), y1 = min(y + 1, HM_ - 1);
    const float* base = look + (size_t)n * HW_;
    float v00 = base[y  * WM_ + x];
    float v01 = base[y  * WM_ + x1];
    float v10 = base[y1 * WM_ + x];
    float v11 = base[y1 * WM_ + x1];
    uint2 q;
    q.x = f2bf(v00) | (f2bf(v01) << 16);
    q.y = f2bf(v10) | (f2bf(v11) << 16);
    quad[t] = q;
}

// ---------------------------------------------------------------------------
// Precompute P = (K @ T)[:3] per (b,f) (12 floats each) and pose validity.
// ---------------------------------------------------------------------------
__global__ void setup_proj(const float* __restrict__ poses,
                           const float* __restrict__ K,
                           float* __restrict__ Pout,      // [B*F][12]
                           float* __restrict__ validOut)  // [B*F]
{
    int t = threadIdx.x;
    if (t < B_ * F_ * 12) {
        int j  = t & 3;
        int i  = (t >> 2) % 3;
        int bf = t / 12;
        int b  = bf / F_;
        const float* Kb = K + (size_t)b * 16;
        const float* T  = poses + (size_t)bf * 16;
        float s = 0.f;
        #pragma unroll
        for (int k = 0; k < 4; ++k) s += Kb[i * 4 + k] * T[k * 4 + j];
        Pout[bf * 12 + i * 4 + j] = s;
    }
    if (t < B_ * F_) {
        const float* T = poses + (size_t)t * 16;
        float s = 0.f;
        #pragma unroll
        for (int k = 0; k < 16; ++k) s += T[k];
        validOut[t] = (s != 0.0f) ? 1.0f : 0.0f;
    }
}

// ---------------------------------------------------------------------------
// Main cost-volume kernel. One thread per output (b,d,hw).
//  * edge-active lanes have gx in [2,158], gy in [2,46] => quad (x0,y0) is a
//    fully valid interior quad; inactive lanes use clamped (fault-safe)
//    indices and are zeroed by ff.
//  * per channel: 2 aligned dwordx2 quad loads + 1 dword cur load,
//    u32 byte offsets from uniform bases (saddr form), bump by stride.
// ---------------------------------------------------------------------------
__global__ __launch_bounds__(256) void cost_volume(
    const float* __restrict__ cur,     // [B][C][HW]
    const uint2* __restrict__ quad,    // [B*F][C][HW] packed corner quads
    const float* __restrict__ invK,    // [B][16]
    const float* __restrict__ P,       // [B*F][12]
    const float* __restrict__ validF,  // [B*F]
    float* __restrict__ cvOut)         // [B][D][HW]
{
    int gid  = blockIdx.x * 256 + threadIdx.x;   // exact: B*D*HW = 5760*256
    int hw   = gid % HW_;
    int rest = gid / HW_;      // uniform within a block
    int d    = rest % D_;
    int b    = rest / D_;

    int x = hw % WM_, y = hw / WM_;
    float fx = (float)x, fy = (float)y;

    const float* ik = invK + (size_t)b * 16;
    float rx = ik[0] * fx + ik[1] * fy + ik[2];
    float ry = ik[4] * fx + ik[5] * fy + ik[6];
    float rz = ik[8] * fx + ik[9] * fy + ik[10];

    float depth = 0.1f + (float)d * (19.9f / 95.0f);
    float qx = depth * rx, qy = depth * ry, qz = depth * rz;

    bool inter = (x >= 2 && x <= WM_ - 3 && y >= 2 && y <= HM_ - 3);

    unsigned oq[F_];                     // byte offsets into quad[]
    float w00[F_], w01[F_], w02[F_], w03[F_];
    float ff[F_];

    #pragma unroll
    for (int f = 0; f < F_; ++f) {
        const float* Pf = P + (size_t)(b * F_ + f) * 12;
        float cp0 = Pf[0] * qx + Pf[1] * qy + Pf[2]  * qz + Pf[3];
        float cp1 = Pf[4] * qx + Pf[5] * qy + Pf[6]  * qz + Pf[7];
        float cp2 = Pf[8] * qx + Pf[9] * qy + Pf[10] * qz + Pf[11];
        float z  = cp2 + EPS_;
        float gx = cp0 / z, gy = cp1 / z;

        float x0f = floorf(gx), y0f = floorf(gy);
        float wx1 = gx - x0f, wy1 = gy - y0f;
        float wx0 = 1.f - wx1, wy0 = 1.f - wy1;

        int x0 = (int)x0f, y0 = (int)y0f;
        int cx = min(max(x0, 0), WM_ - 1);
        int cy = min(max(y0, 0), HM_ - 1);

        oq[f] = ((unsigned)((b * F_ + f) * C_ * HW_) +
                 (unsigned)(cy * WM_ + cx)) * 8u;

        w00[f] = wx0 * wy0;
        w01[f] = wx1 * wy0;
        w02[f] = wx0 * wy1;
        w03[f] = wx1 * wy1;

        bool e = (gx >= 2.f) && (gx <= (float)(WM_ - 2)) &&
                 (gy >= 2.f) && (gy <= (float)(HM_ - 2)) && inter;
        ff[f] = (e ? 1.f : 0.f) * validF[b * F_ + f];
    }

    // Wave-uniform early-out
    if (__ballot(ff[0] > 0.f || ff[1] > 0.f) == 0ull) {
        cvOut[(size_t)gid] = 0.f;
        return;
    }

    const char* qb = (const char*)quad;
    const char* cb = (const char*)cur;
    unsigned oq0 = oq[0], oq1 = oq[1];
    unsigned oc  = (unsigned)(b * C_ * HW_ + hw) * 4u;

    float s0 = 0.f, s1 = 0.f;
    #pragma unroll 8
    for (int c = 0; c < C_; ++c) {
        uint2 q0 = *(const uint2*)(qb + oq0); oq0 += HW_ * 8u;
        uint2 q1 = *(const uint2*)(qb + oq1); oq1 += HW_ * 8u;
        float cvv = *(const float*)(cb + oc); oc += HW_ * 4u;

        float f00 = __uint_as_float(q0.x << 16);
        float f01 = __uint_as_float(q0.x & 0xFFFF0000u);
        float f10 = __uint_as_float(q0.y << 16);
        float f11 = __uint_as_float(q0.y & 0xFFFF0000u);
        float g00 = __uint_as_float(q1.x << 16);
        float g01 = __uint_as_float(q1.x & 0xFFFF0000u);
        float g10 = __uint_as_float(q1.y << 16);
        float g11 = __uint_as_float(q1.y & 0xFFFF0000u);

        float a0 = fmaf(w00[0], f00, fmaf(w01[0], f01,
                   fmaf(w02[0], f10, w03[0] * f11)));
        float a1 = fmaf(w00[1], g00, fmaf(w01[1], g01,
                   fmaf(w02[1], g10, w03[1] * g11)));
        s0 += fabsf(a0 - cvv);
        s1 += fabsf(a1 - cvv);
    }

    float m0 = s0 * (1.0f / 64.0f) * ff[0];
    float m1 = s1 * (1.0f / 64.0f) * ff[1];
    float costsum = m0 + m1;
    float counts  = ((m0 > 0.f) ? 1.f : 0.f) + ((m1 > 0.f) ? 1.f : 0.f);
    float scale = (counts > 1.5f) ? (1.0f / (2.0f + EPS_)) : (1.0f / (1.0f + EPS_));
    cvOut[(size_t)gid] = costsum * scale;
}

// ---------------------------------------------------------------------------
// Finalize: per (b,hw), max over D, then write cost / missing.
// ---------------------------------------------------------------------------
__global__ __launch_bounds__(256) void finalize(
    const float* __restrict__ cv,   // [B][D][HW]
    float* __restrict__ cost,       // [B][D][HW]
    float* __restrict__ missing)    // [B][D][HW]
{
    int t = blockIdx.x * blockDim.x + threadIdx.x;
    if (t >= B_ * HW_) return;
    int b = t / HW_, hw = t % HW_;
    const float* src = cv + (size_t)b * D_ * HW_ + hw;

    float mx = 0.f;   // all values >= 0
    for (int d = 0; d < D_; ++d)
        mx = fmaxf(mx, src[(size_t)d * HW_]);

    for (int d = 0; d < D_; ++d) {
        float v = src[(size_t)d * HW_];
        float m = (v == 0.f) ? 1.f : 0.f;
        size_t o = (size_t)b * D_ * HW_ + (size_t)d * HW_ + hw;
        cost[o]    = (m != 0.f) ? mx : v;
        missing[o] = m;
    }
}

// ---------------------------------------------------------------------------
extern "C" void kernel_launch(void* const* d_in, const int* in_sizes, int n_in,
                              void* d_out, int out_size, void* d_ws, size_t ws_size,
                              hipStream_t stream)
{
    const float* current = (const float*)d_in[0];  // [B,C,H,W]
    const float* lookup  = (const float*)d_in[1];  // [B,F,C,H,W]
    const float* poses   = (const float*)d_in[2];  // [B,F,4,4]
    const float* K       = (const float*)d_in[3];  // [B,4,4]
    const float* invK    = (const float*)d_in[4];  // [B,4,4]

    float* out = (float*)d_out;
    float* costOut    = out;                 // [B,D,H,W]
    float* missingOut = out + NTOT;          // [B,D,H,W]
    float* cvOut      = out + 2 * NTOT;      // [B,D,H,W] (pre-fill cost)

    // workspace layout: small params first, then the 15.75 MB quad buffer
    float* ws     = (float*)d_ws;
    float* Pmat   = ws;                      // B*F*12 = 48 floats
    float* validF = Pmat + B_ * F_ * 12;     // B*F    = 4 floats
    uint2* quad   = (uint2*)(ws + 64);       // B*F*C*HW uint2 = 15,728,640 B

    hipLaunchKernelGGL(setup_proj, dim3(1), dim3(64), 0, stream,
                       poses, K, Pmat, validF);

    const int nquad = B_ * F_ * C_ * HW_;        // 1,966,080 = 7680 * 256
    hipLaunchKernelGGL(pack_quads, dim3(nquad / 256), dim3(256), 0, stream,
                       lookup, quad);

    const int total = B_ * D_ * HW_;             // 1,474,560 = 5760 * 256
    hipLaunchKernelGGL(cost_volume, dim3(total / 256), dim3(256), 0, stream,
                       current, quad, invK, Pmat, validF, cvOut);

    const int npix = B_ * HW_;                   // 15,360
    hipLaunchKernelGGL(finalize, dim3((npix + 255) / 256), dim3(256), 0, stream,
                       cvOut, costOut, missingOut);
}

// Round 5
// 127.539 us; speedup vs baseline: 1.5852x; 1.1531x over previous
//
#include <hip/hip_runtime.h>
#include <hip/hip_bf16.h>
#include <stdint.h>

// Problem constants (from reference)
#define B_  2
#define F_  2
#define C_  64
#define D_  96
#define HM_ 48
#define WM_ 160
#define HW_ (HM_ * WM_)                 // 7680
#define NTOT ((size_t)B_ * D_ * HW_)    // 1,474,560 per output tensor
#define EPS_ 1e-7f

typedef _Float16 h2 __attribute__((ext_vector_type(2)));
struct QuadH { h2 r0, r1; };            // 8B: (v00,v01),(v10,v11) as f16

#if __has_builtin(__builtin_amdgcn_fdot2)
__device__ __forceinline__ float FDOT2(h2 a, h2 b, float c) {
    return __builtin_amdgcn_fdot2(a, b, c, false);
}
#else
__device__ __forceinline__ float FDOT2(h2 a, h2 b, float c) {
    return (float)a.x * (float)b.x + (float)a.y * (float)b.y + c;
}
#endif

// ---------------------------------------------------------------------------
// Pack, for each (frame,channel,y,x), the 2x2 bilinear corner quad as 4xf16.
// Border neighbors clamped (only ff==0 lanes ever read those).
// ---------------------------------------------------------------------------
__global__ __launch_bounds__(256) void pack_quads(
    const float* __restrict__ look,   // [B*F*C][HW]
    QuadH* __restrict__ quad)         // [B*F*C*HW]
{
    int t = blockIdx.x * 256 + threadIdx.x;   // exact: B*F*C*HW = 7680*256
    int hw = t % HW_;
    int n  = t / HW_;
    int x = hw % WM_, y = hw / WM_;
    int x1 = min(x + 1, WM_ - 1), y1 = min(y + 1, HM_ - 1);
    const float* base = look + (size_t)n * HW_;
    float v00 = base[y  * WM_ + x];
    float v01 = base[y  * WM_ + x1];
    float v10 = base[y1 * WM_ + x];
    float v11 = base[y1 * WM_ + x1];
    QuadH q;
    q.r0 = h2{(_Float16)v00, (_Float16)v01};
    q.r1 = h2{(_Float16)v10, (_Float16)v11};
    quad[t] = q;
}

// ---------------------------------------------------------------------------
// Precompute P = (K @ T)[:3] per (b,f) (12 floats each) and pose validity.
// ---------------------------------------------------------------------------
__global__ void setup_proj(const float* __restrict__ poses,
                           const float* __restrict__ K,
                           float* __restrict__ Pout,      // [B*F][12]
                           float* __restrict__ validOut)  // [B*F]
{
    int t = threadIdx.x;
    if (t < B_ * F_ * 12) {
        int j  = t & 3;
        int i  = (t >> 2) % 3;
        int bf = t / 12;
        int b  = bf / F_;
        const float* Kb = K + (size_t)b * 16;
        const float* T  = poses + (size_t)bf * 16;
        float s = 0.f;
        #pragma unroll
        for (int k = 0; k < 4; ++k) s += Kb[i * 4 + k] * T[k * 4 + j];
        Pout[bf * 12 + i * 4 + j] = s;
    }
    if (t < B_ * F_) {
        const float* T = poses + (size_t)t * 16;
        float s = 0.f;
        #pragma unroll
        for (int k = 0; k < 16; ++k) s += T[k];
        validOut[t] = (s != 0.0f) ? 1.0f : 0.0f;
    }
}

// ---------------------------------------------------------------------------
// Main cost-volume kernel. One thread per output (b,d,hw).
// Block order: (b,d) fastest, pixel-tile slowest -> the 192 consecutive
// blocks sharing a tile run concurrently, so each XCD's L2 fetches that
// tile's quad/cur region once and serves all depths from L2.
// Per channel: 2 aligned 8B quad loads + 1 dword cur load,
//              2x(2 v_dot2_f32_f16 + 1 abs-add) -- no unpack.
// ---------------------------------------------------------------------------
__global__ __launch_bounds__(256) void cost_volume(
    const float* __restrict__ cur,     // [B][C][HW]
    const QuadH* __restrict__ quad,    // [B*F][C][HW] packed corner quads
    const float* __restrict__ invK,    // [B][16]
    const float* __restrict__ P,       // [B*F][12]
    const float* __restrict__ validF,  // [B*F]
    float* __restrict__ cvOut)         // [B][D][HW]
{
    int blk  = blockIdx.x;          // 5760 = 30 tiles * (B*D = 192)
    int tile = blk / (B_ * D_);
    int r    = blk % (B_ * D_);
    int b    = r / D_;
    int d    = r % D_;
    int hw   = tile * 256 + threadIdx.x;

    int x = hw % WM_, y = hw / WM_;
    float fx = (float)x, fy = (float)y;

    const float* ik = invK + (size_t)b * 16;
    float rx = ik[0] * fx + ik[1] * fy + ik[2];
    float ry = ik[4] * fx + ik[5] * fy + ik[6];
    float rz = ik[8] * fx + ik[9] * fy + ik[10];

    float depth = 0.1f + (float)d * (19.9f / 95.0f);
    float qx = depth * rx, qy = depth * ry, qz = depth * rz;

    bool inter = (x >= 2 && x <= WM_ - 3 && y >= 2 && y <= HM_ - 3);

    unsigned oq[F_];                 // byte offsets into quad[]
    h2 w01[F_], w23[F_];             // packed f16 bilinear weights
    float ff[F_];

    #pragma unroll
    for (int f = 0; f < F_; ++f) {
        const float* Pf = P + (size_t)(b * F_ + f) * 12;
        float cp0 = Pf[0] * qx + Pf[1] * qy + Pf[2]  * qz + Pf[3];
        float cp1 = Pf[4] * qx + Pf[5] * qy + Pf[6]  * qz + Pf[7];
        float cp2 = Pf[8] * qx + Pf[9] * qy + Pf[10] * qz + Pf[11];
        float z  = cp2 + EPS_;
        float gx = cp0 / z, gy = cp1 / z;

        float x0f = floorf(gx), y0f = floorf(gy);
        float wx1 = gx - x0f, wy1 = gy - y0f;
        float wx0 = 1.f - wx1, wy0 = 1.f - wy1;

        int x0 = (int)x0f, y0 = (int)y0f;
        int cx = min(max(x0, 0), WM_ - 1);
        int cy = min(max(y0, 0), HM_ - 1);

        oq[f] = ((unsigned)((b * F_ + f) * C_ * HW_) +
                 (unsigned)(cy * WM_ + cx)) * 8u;

        w01[f] = h2{(_Float16)(wx0 * wy0), (_Float16)(wx1 * wy0)};
        w23[f] = h2{(_Float16)(wx0 * wy1), (_Float16)(wx1 * wy1)};

        bool e = (gx >= 2.f) && (gx <= (float)(WM_ - 2)) &&
                 (gy >= 2.f) && (gy <= (float)(HM_ - 2)) && inter;
        ff[f] = (e ? 1.f : 0.f) * validF[b * F_ + f];
    }

    size_t oidx = ((size_t)(b * D_ + d)) * HW_ + hw;

    // Wave-uniform early-out
    if (__ballot(ff[0] > 0.f || ff[1] > 0.f) == 0ull) {
        cvOut[oidx] = 0.f;
        return;
    }

    const char* qb = (const char*)quad;
    const char* cb = (const char*)cur;
    unsigned oq0 = oq[0], oq1 = oq[1];
    unsigned oc  = (unsigned)(b * C_ * HW_ + hw) * 4u;

    h2 w01_0 = w01[0], w23_0 = w23[0];
    h2 w01_1 = w01[1], w23_1 = w23[1];

    float s0 = 0.f, s1 = 0.f;
    #pragma unroll 8
    for (int c = 0; c < C_; ++c) {
        QuadH q0 = *(const QuadH*)(qb + oq0); oq0 += HW_ * 8u;
        QuadH q1 = *(const QuadH*)(qb + oq1); oq1 += HW_ * 8u;
        float cvv = *(const float*)(cb + oc); oc += HW_ * 4u;
        float ncvv = -cvv;

        float a0 = FDOT2(q0.r0, w01_0, FDOT2(q0.r1, w23_0, ncvv));
        float a1 = FDOT2(q1.r0, w01_1, FDOT2(q1.r1, w23_1, ncvv));
        s0 += fabsf(a0);
        s1 += fabsf(a1);
    }

    float m0 = s0 * (1.0f / 64.0f) * ff[0];
    float m1 = s1 * (1.0f / 64.0f) * ff[1];
    float costsum = m0 + m1;
    float counts  = ((m0 > 0.f) ? 1.f : 0.f) + ((m1 > 0.f) ? 1.f : 0.f);
    float scale = (counts > 1.5f) ? (1.0f / (2.0f + EPS_)) : (1.0f / (1.0f + EPS_));
    cvOut[oidx] = costsum * scale;
}

// ---------------------------------------------------------------------------
// Finalize: per (b,hw), max over D, then write cost / missing.
// ---------------------------------------------------------------------------
__global__ __launch_bounds__(256) void finalize(
    const float* __restrict__ cv,   // [B][D][HW]
    float* __restrict__ cost,       // [B][D][HW]
    float* __restrict__ missing)    // [B][D][HW]
{
    int t = blockIdx.x * blockDim.x + threadIdx.x;
    if (t >= B_ * HW_) return;
    int b = t / HW_, hw = t % HW_;
    const float* src = cv + (size_t)b * D_ * HW_ + hw;

    float mx = 0.f;   // all values >= 0
    for (int d = 0; d < D_; ++d)
        mx = fmaxf(mx, src[(size_t)d * HW_]);

    for (int d = 0; d < D_; ++d) {
        float v = src[(size_t)d * HW_];
        float m = (v == 0.f) ? 1.f : 0.f;
        size_t o = (size_t)b * D_ * HW_ + (size_t)d * HW_ + hw;
        cost[o]    = (m != 0.f) ? mx : v;
        missing[o] = m;
    }
}

// ---------------------------------------------------------------------------
extern "C" void kernel_launch(void* const* d_in, const int* in_sizes, int n_in,
                              void* d_out, int out_size, void* d_ws, size_t ws_size,
                              hipStream_t stream)
{
    const float* current = (const float*)d_in[0];  // [B,C,H,W]
    const float* lookup  = (const float*)d_in[1];  // [B,F,C,H,W]
    const float* poses   = (const float*)d_in[2];  // [B,F,4,4]
    const float* K       = (const float*)d_in[3];  // [B,4,4]
    const float* invK    = (const float*)d_in[4];  // [B,4,4]

    float* out = (float*)d_out;
    float* costOut    = out;                 // [B,D,H,W]
    float* missingOut = out + NTOT;          // [B,D,H,W]
    float* cvOut      = out + 2 * NTOT;      // [B,D,H,W] (pre-fill cost)

    // workspace layout: small params first, then the 15.75 MB quad buffer
    float* ws     = (float*)d_ws;
    float* Pmat   = ws;                      // B*F*12 = 48 floats
    float* validF = Pmat + B_ * F_ * 12;     // B*F    = 4 floats
    QuadH* quad   = (QuadH*)(ws + 64);       // B*F*C*HW QuadH = 15,728,640 B

    hipLaunchKernelGGL(setup_proj, dim3(1), dim3(64), 0, stream,
                       poses, K, Pmat, validF);

    const int nquad = B_ * F_ * C_ * HW_;        // 1,966,080 = 7680 * 256
    hipLaunchKernelGGL(pack_quads, dim3(nquad / 256), dim3(256), 0, stream,
                       lookup, quad);

    const int total = B_ * D_ * HW_;             // 1,474,560 = 5760 * 256
    hipLaunchKernelGGL(cost_volume, dim3(total / 256), dim3(256), 0, stream,
                       current, quad, invK, Pmat, validF, cvOut);

    const int npix = B_ * HW_;                   // 15,360
    hipLaunchKernelGGL(finalize, dim3((npix + 255) / 256), dim3(256), 0, stream,
                       cvOut, costOut, missingOut);
}